// Round 4
// baseline (1343.463 us; speedup 1.0000x reference)
//
#include <hip/hip_runtime.h>
#include <stdint.h>

#define NN 16384   // nodes
#define NC 16      // colors
#define NB 64      // graphs

// open-addressing hash table: h (64-bit) -> min node index
#define HSIZE 65536
#define HMASK 65535
#define HSENT 0xFFFFFFFFFFFFFFFFull
#define HGOLD 0x9E3779B97F4A7C15ull

typedef unsigned int vuint4 __attribute__((ext_vector_type(4)));  // native vec for nontemporal builtin

struct Mults { unsigned long long m[17]; };

__device__ __forceinline__ void htab_insert(unsigned long long* __restrict__ hk,
                                            int* __restrict__ hv,
                                            unsigned long long key, int idx) {
  if (key == HSENT) key -= 1;                    // sentinel nudge (prob ~2^-64, same class risk as ref's 64-bit hash)
  unsigned slot = (unsigned)((key * HGOLD) >> 48);
  for (;;) {
    unsigned long long old = atomicCAS(&hk[slot], HSENT, key);
    if (old == HSENT || old == key) { atomicMin(&hv[slot], idx); return; }
    slot = (slot + 1) & HMASK;
  }
}

// ---------------- kernels ----------------

// Build per-64-column color bitmasks matching the ballot bit layout of k_hist,
// zero scount, and init the hash table. (cnt buffer is gone: the per-graph
// histogram now lives in k_emit_norm's LDS.)
// grid = 256 x 256 threads.
__global__ __launch_bounds__(256) void k_init(const int* __restrict__ x,
                                              unsigned long long* __restrict__ table,
                                              int* __restrict__ scount,
                                              unsigned long long* __restrict__ hk,
                                              int* __restrict__ hv) {
  int idx = blockIdx.x * 256 + threadIdx.x;        // [0, 65536)
  if (idx == 0) *scount = 0;
  if (idx < 4096) {
    int c = idx & 15, k = (idx >> 4) & 3, chunk = idx >> 6;
    unsigned long long m = 0ull;
    for (int l = 0; l < 64; ++l) {
      int col = chunk * 256 + l * 4 + k;
      if (x[col] == c) m |= (1ull << l);
    }
    table[idx] = m;
  }
  // hash table init: 65536 slots, one per thread
  hk[idx] = HSENT;
  hv[idx] = 0x7fffffff;
}

// One wave per row: neighbor color histogram via ballots + mask popcounts.
// Explicit software pipeline: double-buffered 4-deep lookahead with named
// registers (static indexing only) -- the next batch's loads are issued
// BEFORE the current batch is consumed, so loads never drain at batch
// boundaries (the round-3 batch-of-8 pattern drained 8x per row).
// Note table index: k*16+c == lane, so the mask load is a fully coalesced
// 512 B/wave load (L1-resident, 32 KiB table).
#define NTLOAD(dv, dt, ch) \
    dv = __builtin_nontemporal_load(&rowp[(ch) * 64 + lane]); \
    dt = tkl[(ch) * 64];

#define CONSUME(v, tm) { \
    unsigned long long b0 = __ballot(v.x != 0u); \
    unsigned long long b1 = __ballot(v.y != 0u); \
    unsigned long long b2 = __ballot(v.z != 0u); \
    unsigned long long b3 = __ballot(v.w != 0u); \
    unsigned long long m = (k & 2) ? ((k & 1) ? b3 : b2) : ((k & 1) ? b1 : b0); \
    cnt += __popcll(m & tm); }

__global__ __launch_bounds__(256) void k_hist(const float* __restrict__ adj,
                                              const unsigned long long* __restrict__ table,
                                              const int* __restrict__ x,
                                              Mults M,
                                              unsigned long long* __restrict__ h,
                                              int* __restrict__ iso,
                                              int* __restrict__ suspects,
                                              int* __restrict__ scount,
                                              unsigned long long* __restrict__ hk,
                                              int* __restrict__ hv) {
  int wave = threadIdx.x >> 6;
  int lane = threadIdx.x & 63;
  int row  = blockIdx.x * 4 + wave;
  int xv   = x[row];
  const vuint4* rowp = (const vuint4*)(adj + (size_t)row * NN);
  int k = lane >> 4;                               // k-slice 0..3
  const unsigned long long* tkl = table + lane;    // k*16+c == lane
  int cnt = 0;

  vuint4 va0, va1, va2, va3, vb0, vb1, vb2, vb3;
  unsigned long long ta0, ta1, ta2, ta3, tb0, tb1, tb2, tb3;
  NTLOAD(va0, ta0, 0) NTLOAD(va1, ta1, 1) NTLOAD(va2, ta2, 2) NTLOAD(va3, ta3, 3)
  #pragma unroll
  for (int cc = 0; cc < 64; cc += 8) {
    NTLOAD(vb0, tb0, cc + 4) NTLOAD(vb1, tb1, cc + 5)
    NTLOAD(vb2, tb2, cc + 6) NTLOAD(vb3, tb3, cc + 7)
    CONSUME(va0, ta0) CONSUME(va1, ta1) CONSUME(va2, ta2) CONSUME(va3, ta3)
    if (cc + 8 < 64) {
      NTLOAD(va0, ta0, cc + 8) NTLOAD(va1, ta1, cc + 9)
      NTLOAD(va2, ta2, cc + 10) NTLOAD(va3, ta3, cc + 11)
    }
    CONSUME(vb0, tb0) CONSUME(vb1, tb1) CONSUME(vb2, tb2) CONSUME(vb3, tb3)
  }

  // fold the 4 k-slices: every lane now holds hist[lane & 15]
  cnt += __shfl_xor(cnt, 16, 64);
  cnt += __shfl_xor(cnt, 32, 64);
  // rowsum (within each 16-lane group = sum over all 16 colors)
  int rs = cnt;
  rs += __shfl_xor(rs, 1, 64);
  rs += __shfl_xor(rs, 2, 64);
  rs += __shfl_xor(rs, 4, 64);
  rs += __shfl_xor(rs, 8, 64);
  // polynomial hash: sum over c of hist[c] * M[c+1]
  unsigned long long hl = (unsigned long long)(long long)cnt * M.m[(lane & 15) + 1];
  hl += __shfl_xor(hl, 1, 64);
  hl += __shfl_xor(hl, 2, 64);
  hl += __shfl_xor(hl, 4, 64);
  hl += __shfl_xor(hl, 8, 64);
  if (lane == 0) {
    unsigned long long hf = hl + (unsigned long long)(long long)xv * M.m[0];
    h[row] = hf;
    if (rs == 0) {
      int s = atomicAdd(scount, 1);
      suspects[s] = row;                 // h not final until colcheck; insert deferred there
    } else {
      htab_insert(hk, hv, hf, row);
    }
  }
  if (lane == 1) iso[row] = 0;
}

// Check columns of suspect nodes only (exits immediately if no suspects).
// Confirmed isolates get iso=1; unconfirmed suspects get their h inserted
// into the hash table (their h from k_hist is final).
__global__ __launch_bounds__(256) void k_colcheck(const float* __restrict__ adj,
                                                  const int* __restrict__ suspects,
                                                  const int* __restrict__ scount,
                                                  int* __restrict__ iso,
                                                  const unsigned long long* __restrict__ h,
                                                  unsigned long long* __restrict__ hk,
                                                  int* __restrict__ hv) {
  __shared__ int red[256];
  int nsus = *scount;
  for (int u = blockIdx.x; u < nsus; u += gridDim.x) {
    int col = suspects[u];
    int any = 0;
    for (int r = threadIdx.x; r < NN; r += 256)
      any |= (adj[(size_t)r * NN + col] != 0.0f);
    red[threadIdx.x] = any;
    __syncthreads();
    for (int s = 128; s > 0; s >>= 1) {
      if (threadIdx.x < s) red[threadIdx.x] |= red[threadIdx.x + s];
      __syncthreads();
    }
    if (threadIdx.x == 0) {
      if (red[0] == 0) iso[col] = 1;
      else             htab_insert(hk, hv, h[col], col);
    }
    __syncthreads();
  }
}

// Grid-parallel hash lookup: firsts[i] = min{ j : h[j]==h[i] }, -1 for
// isolates. Also emits per-block is_first sums (partial[bid]) for the
// cross-block rank prefix in k_rank.
__global__ __launch_bounds__(256) void k_lookup(const int* __restrict__ iso,
                                                const unsigned long long* __restrict__ h,
                                                const unsigned long long* __restrict__ hk,
                                                const int* __restrict__ hv,
                                                int* __restrict__ firsts,
                                                int* __restrict__ partial) {
  __shared__ int red[256];
  int i = blockIdx.x * 256 + threadIdx.x;
  int f = -1;
  if (!iso[i]) {
    unsigned long long key = h[i];
    if (key == HSENT) key -= 1;                  // must match insert-side nudge
    unsigned slot = (unsigned)((key * HGOLD) >> 48);
    unsigned long long kk = hk[slot];
    while (kk != key) { slot = (slot + 1) & HMASK; kk = hk[slot]; }
    f = hv[slot];                                // guaranteed present & final
  }
  firsts[i] = f;
  red[threadIdx.x] = (f == i);
  __syncthreads();
  for (int s = 128; s > 0; s >>= 1) {
    if (threadIdx.x < s) red[threadIdx.x] += red[threadIdx.x + s];
    __syncthreads();
  }
  if (threadIdx.x == 0) partial[blockIdx.x] = red[0];
}

// rank[i] = inclusive cumsum of is_first at i (64 blocks x 256 threads).
// Block base from partial[]; block-local scan via wave shfl + LDS.
__global__ __launch_bounds__(256) void k_rank(const int* __restrict__ firsts,
                                              const int* __restrict__ partial,
                                              int* __restrict__ rank) {
  __shared__ int wsum[4];
  __shared__ int sbase;
  int t = threadIdx.x;
  int lane = t & 63, wv = t >> 6;
  int i = blockIdx.x * 256 + t;
  int isf = (firsts[i] == i);                    // isolates: firsts=-1 -> 0
  // wave-inclusive scan
  int incl = isf;
  #pragma unroll
  for (int off = 1; off < 64; off <<= 1) {
    int v = __shfl_up(incl, off, 64);
    if (lane >= off) incl += v;
  }
  if (lane == 63) wsum[wv] = incl;
  // cross-block base: sum of partial[0..bid-1], computed by wave 0
  if (t < 64) {
    int p = (t < blockIdx.x) ? partial[t] : 0;
    p += __shfl_xor(p, 1, 64);
    p += __shfl_xor(p, 2, 64);
    p += __shfl_xor(p, 4, 64);
    p += __shfl_xor(p, 8, 64);
    p += __shfl_xor(p, 16, 64);
    p += __shfl_xor(p, 32, 64);
    if (t == 0) sbase = p;
  }
  __syncthreads();
  int wbase = 0;
  #pragma unroll
  for (int w = 0; w < 4; ++w)
    if (w < wv) wbase += wsum[w];
  rank[i] = sbase + wbase + incl;
}

// One block per graph. batch is SORTED, so graph b owns a contiguous node
// range [lb(b), lb(b+1)) found by binary search. The per-graph color
// histogram lives in LDS (64 KiB) -- atomics are LDS-local across 64 CUs
// instead of global from 1 CU -- and L2 normalization is fused in the same
// kernel. The 4 MiB global cnt buffer (zero + atomic + read) is gone.
__global__ __launch_bounds__(256) void k_emit_norm(const int* __restrict__ firsts,
                                                   const int* __restrict__ rank,
                                                   const int* __restrict__ batch,
                                                   float* __restrict__ out_colors,
                                                   float* __restrict__ out) {
  __shared__ __align__(16) int lhist[NN];   // 64 KiB
  __shared__ float red[256];
  __shared__ int range[2];
  int b = blockIdx.x;
  int tid = threadIdx.x;
  int4* lh4 = (int4*)lhist;
  int4 z = {0, 0, 0, 0};
  for (int j = tid; j < NN / 4; j += 256) lh4[j] = z;
  if (tid < 2) {
    int target = b + tid;
    int lo = 0, hi = NN;
    while (lo < hi) { int mid = (lo + hi) >> 1; if (batch[mid] < target) lo = mid + 1; else hi = mid; }
    range[tid] = lo;
  }
  __syncthreads();
  int lo = range[0], hi = range[1];
  for (int i = lo + tid; i < hi; i += 256) {
    int f = firsts[i];
    int c = (f < 0) ? 0 : rank[f];
    out_colors[i] = (float)c;
    if (c > 0) atomicAdd(&lhist[c - 1], 1);
  }
  __syncthreads();
  // square-sum (same strided int4 order as the old k_norm -> identical rounding)
  float ss = 0.0f;
  const int4* c4 = (const int4*)lhist;
  for (int j = tid; j < NN / 4; j += 256) {
    int4 v = c4[j];
    float4 f = {(float)v.x, (float)v.y, (float)v.z, (float)v.w};
    ss += f.x * f.x + f.y * f.y + f.z * f.z + f.w * f.w;
  }
  red[tid] = ss;
  __syncthreads();
  for (int s = 128; s > 0; s >>= 1) {
    if (tid < s) red[tid] += red[tid + s];
    __syncthreads();
  }
  float inv = 1.0f / sqrtf(red[0]);
  float4* o4 = (float4*)(out + (size_t)b * NN);
  for (int j = tid; j < NN / 4; j += 256) {
    int4 v = c4[j];
    float4 f = {(float)v.x * inv, (float)v.y * inv, (float)v.z * inv, (float)v.w * inv};
    o4[j] = f;
  }
}

// ---------------- host: numpy RandomState(42) MULTS replication ----------------

struct MTState { uint32_t mt[624]; int idx; };

static void mt_seed(MTState& s, uint32_t seed) {
  s.mt[0] = seed;
  for (int i = 1; i < 624; ++i)
    s.mt[i] = 1812433253u * (s.mt[i - 1] ^ (s.mt[i - 1] >> 30)) + (uint32_t)i;
  s.idx = 624;
}

static uint32_t mt_next(MTState& s) {
  if (s.idx >= 624) {
    for (int i = 0; i < 624; ++i) {
      uint32_t y = (s.mt[i] & 0x80000000u) | (s.mt[(i + 1) % 624] & 0x7fffffffu);
      uint32_t nx = s.mt[(i + 397) % 624] ^ (y >> 1);
      if (y & 1u) nx ^= 2567483615u;
      s.mt[i] = nx;
    }
    s.idx = 0;
  }
  uint32_t y = s.mt[s.idx++];
  y ^= y >> 11;
  y ^= (y << 7) & 2636928640u;
  y ^= (y << 15) & 4022730752u;
  y ^= y >> 18;
  return y;
}

static uint64_t mt_next64(MTState& s) {
  uint64_t hi = mt_next(s);
  uint64_t lo = mt_next(s);
  return (hi << 32) | lo;
}

// ---------------- launch ----------------

extern "C" void kernel_launch(void* const* d_in, const int* in_sizes, int n_in,
                              void* d_out, int out_size, void* d_ws, size_t ws_size,
                              hipStream_t stream) {
  const int*   x     = (const int*)d_in[0];
  const float* adj   = (const float*)d_in[1];
  const int*   batch = (const int*)d_in[2];
  float* out_hist   = (float*)d_out;                    // [NB, NN]
  float* out_colors = out_hist + (size_t)NB * NN;       // [NN]

  char* ws = (char*)d_ws;
  int*                scount   = (int*)(ws + 0);          // 4 B
  int*                partial  = (int*)(ws + 256);        // 256 B
  int*                suspects = (int*)(ws + 65536);      // 64 KiB
  unsigned long long* h        = (unsigned long long*)(ws + 131072);  // 128 KiB
  int*                iso      = (int*)(ws + 262144);     // 64 KiB
  int*                firsts   = (int*)(ws + 327680);     // 64 KiB
  int*                rank     = (int*)(ws + 393216);     // 64 KiB
  unsigned long long* table    = (unsigned long long*)(ws + 458752);  // 32 KiB
  unsigned long long* hk       = (unsigned long long*)(ws + 524288);  // 512 KiB hash keys
  int*                hv       = (int*)(ws + 1048576);    // 256 KiB hash values (min idx)

  // Replicate np.random.RandomState(42).randint(1, 2**62, 17) << 1 | 1
  // (legacy masked rejection: mask = 2^62-1, accept <= 2^62-2, high word first)
  Mults M;
  {
    MTState st;
    mt_seed(st, 42u);
    const uint64_t mask62 = (1ull << 62) - 1ull;
    const uint64_t rng    = (1ull << 62) - 2ull;
    for (int i = 0; i < 17; ++i) {
      uint64_t v;
      do { v = mt_next64(st) & mask62; } while (v > rng);
      M.m[i] = ((1ull + v) << 1) | 1ull;
    }
  }

  k_init<<<256, 256, 0, stream>>>(x, table, scount, hk, hv);
  k_hist<<<NN / 4, 256, 0, stream>>>(adj, table, x, M, h, iso, suspects, scount, hk, hv);
  k_colcheck<<<64, 256, 0, stream>>>(adj, suspects, scount, iso, h, hk, hv);
  k_lookup<<<NN / 256, 256, 0, stream>>>(iso, h, hk, hv, firsts, partial);
  k_rank<<<NN / 256, 256, 0, stream>>>(firsts, partial, rank);
  k_emit_norm<<<NB, 256, 0, stream>>>(firsts, rank, batch, out_colors, out_hist);
}